// Round 1
// baseline (134.860 us; speedup 1.0000x reference)
//
#include <hip/hip_runtime.h>
#include <hip/hip_bf16.h>

typedef __attribute__((ext_vector_type(8))) short short8;
typedef __attribute__((ext_vector_type(4))) float f32x4;

#define N_U 8192
#define N_I 8192
#define KD  256

// global_load_lds, 16B per lane. Integer-cast route: AS1 ptr is 64-bit (same
// bits as generic global); AS3 ptr is 32-bit (low 32 bits of generic LDS ptr).
#define GLD16(g, l) __builtin_amdgcn_global_load_lds( \
    (const __attribute__((address_space(1))) unsigned int*)(unsigned long long)(uintptr_t)(g), \
    (__attribute__((address_space(3))) unsigned int*)(unsigned int)(uintptr_t)(l), 16, 0, 0)

static __device__ __forceinline__ unsigned short f2bf(float x) {
  unsigned u = __builtin_bit_cast(unsigned, x);
  u += 0x7fffu + ((u >> 16) & 1u);   // round-to-nearest-even
  return (unsigned short)(u >> 16);
}

static __device__ __forceinline__ void block_reduce_atomic(float v, float* dst) {
  #pragma unroll
  for (int off = 32; off > 0; off >>= 1) v += __shfl_down(v, off, 64);
  __shared__ float red[4];
  int lane = threadIdx.x & 63, wv = threadIdx.x >> 6;
  if (lane == 0) red[wv] = v;
  __syncthreads();
  if (threadIdx.x == 0) atomicAdd(dst, red[0] + red[1] + red[2] + red[3]);
}

// A = P.T (elementwise*) U  -> bf16 [N_U][KD]; also accumulates sum(U^2)+sum(P^2).
// 64(u) x 64(k) tile per block; P tile staged through LDS so both the P read
// (row-major along u) and the A write (along k) coalesce.
__global__ __launch_bounds__(256) void pack_a_kernel(
    const float* __restrict__ U, const float* __restrict__ P,
    unsigned short* __restrict__ Abf, float* __restrict__ regsum)
{
  __shared__ float Pt[64][65];   // +1 pad
  const int u0 = blockIdx.x * 64;
  const int k0 = blockIdx.y * 64;
  const int t = threadIdx.x;
  float ss = 0.f;
  {
    const int ul4 = (t & 15) * 4, klb = t >> 4;
    #pragma unroll
    for (int pass = 0; pass < 4; ++pass) {
      int kl = klb + pass * 16;
      float4 pv = *(const float4*)&P[(size_t)(k0 + kl) * N_U + u0 + ul4];
      Pt[kl][ul4 + 0] = pv.x; Pt[kl][ul4 + 1] = pv.y;
      Pt[kl][ul4 + 2] = pv.z; Pt[kl][ul4 + 3] = pv.w;
      ss += pv.x * pv.x + pv.y * pv.y + pv.z * pv.z + pv.w * pv.w;
    }
  }
  __syncthreads();
  {
    const int k4 = (t & 15) * 4, ulb = t >> 4;
    #pragma unroll
    for (int pass = 0; pass < 4; ++pass) {
      int ul = ulb + pass * 16;
      float4 uv = *(const float4*)&U[(size_t)(u0 + ul) * KD + k0 + k4];
      ss += uv.x * uv.x + uv.y * uv.y + uv.z * uv.z + uv.w * uv.w;
      ushort4 w;
      w.x = f2bf(uv.x * Pt[k4 + 0][ul]);
      w.y = f2bf(uv.y * Pt[k4 + 1][ul]);
      w.z = f2bf(uv.z * Pt[k4 + 2][ul]);
      w.w = f2bf(uv.w * Pt[k4 + 3][ul]);
      *(ushort4*)&Abf[(size_t)(u0 + ul) * KD + k0 + k4] = w;
    }
  }
  block_reduce_atomic(ss, regsum);
}

// V -> bf16, accumulating sum(V^2).
__global__ __launch_bounds__(256) void pack_v_kernel(
    const float* __restrict__ V, unsigned short* __restrict__ Vbf,
    float* __restrict__ regsum)
{
  size_t i = ((size_t)blockIdx.x * 256 + threadIdx.x) * 4;
  float4 v = *(const float4*)&V[i];
  float ss = v.x * v.x + v.y * v.y + v.z * v.z + v.w * v.w;
  ushort4 w;
  w.x = f2bf(v.x); w.y = f2bf(v.y); w.z = f2bf(v.z); w.w = f2bf(v.w);
  *(ushort4*)&Vbf[i] = w;
  block_reduce_atomic(ss, regsum);
}

// 128x128 output tile, BK=32, 4 waves (2x2), mfma_f32_16x16x32_bf16.
// Epilogue: read the 128x128 R tile, accumulate (R - pred)^2 over R!=0,
// block-reduce, one atomicAdd per block. predicted never touches HBM.
__global__ __launch_bounds__(256) void gemm_loss_kernel(
    const float* __restrict__ R, const unsigned short* __restrict__ Abf,
    const unsigned short* __restrict__ Vbf, float* __restrict__ err_acc)
{
  __shared__ unsigned short As[128 * 32];
  __shared__ unsigned short Bs[128 * 32];
  const int tid = threadIdx.x;
  const int wv = tid >> 6, lane = tid & 63;
  const int brow = blockIdx.x, bcol = blockIdx.y;
  const int wr = wv >> 1, wc = wv & 1;

  f32x4 acc[4][4] = {};

  const unsigned short* Ag = Abf + (size_t)brow * 128 * KD;
  const unsigned short* Bg = Vbf + (size_t)bcol * 128 * KD;
  const int f0 = (wv * 2 + 0) * 64 + lane;   // 16B-chunk index 0..511
  const int f1 = f0 + 64;
  const int r0 = lane & 15, kc = (lane >> 4) * 8;

  for (int kt = 0; kt < KD; kt += 32) {
    __syncthreads();
    GLD16(Ag + ((f0 >> 2) * KD + kt + (f0 & 3) * 8), &As[f0 * 8]);
    GLD16(Bg + ((f0 >> 2) * KD + kt + (f0 & 3) * 8), &Bs[f0 * 8]);
    GLD16(Ag + ((f1 >> 2) * KD + kt + (f1 & 3) * 8), &As[f1 * 8]);
    GLD16(Bg + ((f1 >> 2) * KD + kt + (f1 & 3) * 8), &Bs[f1 * 8]);
    __syncthreads();
    short8 a[4], b[4];
    #pragma unroll
    for (int m = 0; m < 4; ++m)
      a[m] = *(const short8*)&As[(wr * 64 + m * 16 + r0) * 32 + kc];
    #pragma unroll
    for (int n = 0; n < 4; ++n)
      b[n] = *(const short8*)&Bs[(wc * 64 + n * 16 + r0) * 32 + kc];
    #pragma unroll
    for (int m = 0; m < 4; ++m)
      #pragma unroll
      for (int n = 0; n < 4; ++n)
        acc[m][n] = __builtin_amdgcn_mfma_f32_16x16x32_bf16(a[m], b[n], acc[m][n], 0, 0, 0);
  }

  // C/D layout (m89-verified): col = lane&15, row = (lane>>4)*4 + j
  float lsum = 0.f;
  const int rowbase = brow * 128 + wr * 64 + (lane >> 4) * 4;
  const size_t colbase = (size_t)bcol * 128 + wc * 64 + (lane & 15);
  #pragma unroll
  for (int m = 0; m < 4; ++m) {
    #pragma unroll
    for (int n = 0; n < 4; ++n) {
      const float* rp = R + (size_t)(rowbase + m * 16) * N_I + colbase + n * 16;
      #pragma unroll
      for (int j = 0; j < 4; ++j) {
        float rv = rp[(size_t)j * N_I];
        if (rv != 0.f) { float d = rv - acc[m][n][j]; lsum += d * d; }
      }
    }
  }
  block_reduce_atomic(lsum, err_acc);
}

__global__ void finalize_kernel(const float* __restrict__ ws, float* __restrict__ out) {
  // loss = err/2 + 0.1/2 * (sumU2 + sumV2 + sumP2)
  out[0] = 0.5f * ws[0] + 0.05f * ws[1];
}

extern "C" void kernel_launch(void* const* d_in, const int* in_sizes, int n_in,
                              void* d_out, int out_size, void* d_ws, size_t ws_size,
                              hipStream_t stream) {
  const float* R = (const float*)d_in[0];
  const float* U = (const float*)d_in[1];
  const float* V = (const float*)d_in[2];
  // d_in[3]=alpha, d_in[4]=Y, d_in[6]=Q: dead w.r.t. the returned value.
  const float* P = (const float*)d_in[5];

  float* ws = (float*)d_ws;                                   // [0]=err, [1]=regsum
  unsigned short* Abf = (unsigned short*)((char*)d_ws + 256); // 4 MiB
  unsigned short* Vbf = Abf + (size_t)N_U * KD;               // 4 MiB
  float* out = (float*)d_out;

  hipMemsetAsync(d_ws, 0, 256, stream);
  pack_a_kernel<<<dim3(N_U / 64, KD / 64), 256, 0, stream>>>(U, P, Abf, ws + 1);
  pack_v_kernel<<<dim3((N_I * KD) / (256 * 4)), 256, 0, stream>>>(V, Vbf, ws + 1);
  gemm_loss_kernel<<<dim3(64, 64), 256, 0, stream>>>(R, Abf, Vbf, ws + 0);
  finalize_kernel<<<1, 1, 0, stream>>>(ws, out);
}